// Round 7
// baseline (331.049 us; speedup 1.0000x reference)
//
#include <hip/hip_runtime.h>
#include <hip/hip_bf16.h>

// Problem constants
#define CC 256      // channels
#define CKD 32      // q/k projection dim
#define NN 4096     // H*W
#define HH 64
#define WW 64
#define BB 4

#define LOG2E 1.44269504088896f
#define EXPSHIFT 23.0831203874f   // 16 * LOG2E

typedef __attribute__((ext_vector_type(8))) short short8;   // 8 bf16 (4 VGPRs)
typedef __attribute__((ext_vector_type(4))) float floatx4;  // MFMA C/D frag

__device__ __forceinline__ unsigned f2bf(float f) {
  union { float f; unsigned u; } v; v.f = f;
  unsigned r = v.u + 0x7fffu + ((v.u >> 16) & 1u);   // RNE
  return r >> 16;
}
__device__ __forceinline__ unsigned f2bf_fast(float f) {
  return (__float_as_uint(f) + 0x8000u) >> 16;  // round, cheap
}
__device__ __forceinline__ float fast_exp2(float x) {
#if __has_builtin(__builtin_amdgcn_exp2f)
  return __builtin_amdgcn_exp2f(x);
#else
  return __expf(x * 0.693147181f);
#endif
}
__device__ __forceinline__ float bf_lo(unsigned u) { return __uint_as_float(u << 16); }
__device__ __forceinline__ float bf_hi(unsigned u) { return __uint_as_float(u & 0xffff0000u); }

// ---------------------------------------------------------------------------
// Kernel 0: pack conv weights Wp[tap][o][c] (tap 9 = 1x1), QKV weights
// Wqkv[inp][o=320][c] (q rows scaled by log2e), Bias[inp][320] (fp32).
// ---------------------------------------------------------------------------
__global__ __launch_bounds__(256) void wpack_kernel(
    const float* __restrict__ wd1, const float* __restrict__ wd3,
    const float* __restrict__ wq1, const float* __restrict__ wk1,
    const float* __restrict__ wv1,
    const float* __restrict__ wq2, const float* __restrict__ wk2,
    const float* __restrict__ wv2,
    const float* __restrict__ bq1, const float* __restrict__ bk1,
    const float* __restrict__ bv1,
    const float* __restrict__ bq2, const float* __restrict__ bk2,
    const float* __restrict__ bv2,
    unsigned short* __restrict__ Wp, unsigned short* __restrict__ Wqkv,
    float* __restrict__ Bias) {
  const int id = blockIdx.x * 256 + threadIdx.x;  // 0..65535
#pragma unroll
  for (int tap = 0; tap < 10; ++tap) {
    float v = (tap < 9) ? wd3[(size_t)id * 9 + tap] : wd1[id];
    Wp[(size_t)tap * (CC * CC) + id] = (unsigned short)f2bf(v);
  }
#pragma unroll
  for (int j = 0; j < 3; ++j) {
    int e = id + j * 65536;
    if (e < 2 * 320 * 256) {
      int inp = e / (320 * 256), rem = e % (320 * 256);
      int o = rem >> 8, c = rem & 255;
      float v;
      if (inp == 0)
        v = (o < 32) ? wq1[o * 256 + c] * LOG2E
            : (o < 64) ? wk1[(o - 32) * 256 + c] : wv1[(o - 64) * 256 + c];
      else
        v = (o < 32) ? wq2[o * 256 + c] * LOG2E
            : (o < 64) ? wk2[(o - 32) * 256 + c] : wv2[(o - 64) * 256 + c];
      Wqkv[e] = (unsigned short)f2bf(v);
    }
  }
  if (id < 640) {
    int inp = id / 320, o = id % 320;
    float v;
    if (inp == 0) v = (o < 32) ? bq1[o] * LOG2E
                      : (o < 64) ? bk1[o - 32] : bv1[o - 64];
    else          v = (o < 32) ? bq2[o] * LOG2E
                      : (o < 64) ? bk2[o - 32] : bv2[o - 64];
    Bias[id] = v;
  }
}

// ---------------------------------------------------------------------------
// Kernel 1: fused xpack + MFMA projections.
// Block (img, pb): 64 pix. Stage x fp32 -> LDS -> bf16 xt[pix][c] (and write
// Xp global). GEMM [64 pix] x [320 o] x [K=256] with A from xt LDS, B = Wqkv
// global. Epilogue repack -> Qp/Kp[b][n][32], Vp[b][n>>3][c][n&7].
// grid (8 img, 64 pb), 256 threads.
// ---------------------------------------------------------------------------
__global__ __launch_bounds__(256) void proj_kernel(
    const float* __restrict__ x1, const float* __restrict__ x2,
    const unsigned short* __restrict__ Wqkv, const float* __restrict__ Bias,
    unsigned short* __restrict__ Xp,
    unsigned short* __restrict__ Qp1, unsigned short* __restrict__ Kp1,
    unsigned short* __restrict__ Vp1,
    unsigned short* __restrict__ Qp2, unsigned short* __restrict__ Kp2,
    unsigned short* __restrict__ Vp2) {
  const int t = threadIdx.x;
  const int w = t >> 6, lane = t & 63;
  const int l15 = lane & 15, g = lane >> 4;
  const int img = blockIdx.x, pb = blockIdx.y;
  const int pix0 = pb * 64;
  const int inp = img >> 2, b = img & 3;
  const float* X = (inp ? x2 : x1) + (size_t)b * CC * NN;
  const unsigned short* Wb = Wqkv + (size_t)inp * 320 * CC;
  const float* Bi = Bias + inp * 320;
  unsigned short* Qp = (inp ? Qp2 : Qp1) + (size_t)b * NN * CKD;
  unsigned short* Kp = (inp ? Kp2 : Kp1) + (size_t)b * NN * CKD;
  unsigned short* Vp = (inp ? Vp2 : Vp1) + (size_t)b * NN * CC;
  unsigned short* Xo = Xp + (size_t)img * NN * CC;

  __shared__ union {
    float ftile[64][65];              // fp32 staging (per 64-c chunk)
    unsigned short otile[320][72];    // output repack [o][pix]
  } pu;
  __shared__ unsigned short xt[64][264];  // bf16 [pix][c], +16B pad

  // ---- stage 4 x 64-c chunks: x -> ftile -> (xt LDS, Xp global)
  const int nl = t & 63, cl0 = t >> 6;
  for (int cb = 0; cb < 4; ++cb) {
    const int c0 = cb * 64;
    if (cb) __syncthreads();
#pragma unroll
    for (int i = 0; i < 16; ++i)
      pu.ftile[cl0 + i * 4][nl] = X[(size_t)(c0 + cl0 + i * 4) * NN + pix0 + nl];
    __syncthreads();
#pragma unroll
    for (int it = 0; it < 2; ++it) {
      int id = it * 256 + t;
      int p = id >> 3, cc = id & 7;
      short8 v;
#pragma unroll
      for (int j = 0; j < 8; ++j) v[j] = (short)f2bf(pu.ftile[cc * 8 + j][p]);
      *(short8*)&xt[p][c0 + cc * 8] = v;
      *(short8*)(Xo + (size_t)(pix0 + p) * CC + c0 + cc * 8) = v;
    }
  }
  __syncthreads();

  // ---- GEMM: A = xt rows (LDS), B = Wqkv rows (global)
  floatx4 acc[4][5];
#pragma unroll
  for (int mf = 0; mf < 4; ++mf)
#pragma unroll
    for (int nf = 0; nf < 5; ++nf) acc[mf][nf] = (floatx4){0.f, 0.f, 0.f, 0.f};
  const int o0w = w * 80;

#pragma unroll
  for (int cb = 0; cb < 8; ++cb) {
    short8 a[4], bfr[5];
#pragma unroll
    for (int mf = 0; mf < 4; ++mf)
      a[mf] = *(const short8*)&xt[mf * 16 + l15][cb * 32 + g * 8];
#pragma unroll
    for (int nf = 0; nf < 5; ++nf)
      bfr[nf] = *(const short8*)(Wb + (size_t)(o0w + nf * 16 + l15) * CC + cb * 32 + g * 8);
#pragma unroll
    for (int nf = 0; nf < 5; ++nf)
#pragma unroll
      for (int mf = 0; mf < 4; ++mf)
        acc[mf][nf] = __builtin_amdgcn_mfma_f32_16x16x32_bf16(
            a[mf], bfr[nf], acc[mf][nf], 0, 0, 0);
  }

  // bias + transposed otile writes
#pragma unroll
  for (int nf = 0; nf < 5; ++nf) {
    float bs = Bi[o0w + nf * 16 + l15];
#pragma unroll
    for (int mf = 0; mf < 4; ++mf) {
      uint2 pk;
      pk.x = f2bf(acc[mf][nf][0] + bs) | (f2bf(acc[mf][nf][1] + bs) << 16);
      pk.y = f2bf(acc[mf][nf][2] + bs) | (f2bf(acc[mf][nf][3] + bs) << 16);
      *(uint2*)&pu.otile[o0w + nf * 16 + l15][mf * 16 + g * 4] = pk;
    }
  }
  __syncthreads();

  {
    const int pix = t >> 2, ch = t & 3;
    short8 vq, vk;
#pragma unroll
    for (int e = 0; e < 8; ++e) {
      vq[e] = (short)pu.otile[ch * 8 + e][pix];
      vk[e] = (short)pu.otile[32 + ch * 8 + e][pix];
    }
    *(short8*)(Qp + (size_t)(pix0 + pix) * CKD + ch * 8) = vq;
    *(short8*)(Kp + (size_t)(pix0 + pix) * CKD + ch * 8) = vk;
  }
#pragma unroll
  for (int it = 0; it < 8; ++it) {
    short8 vv = *(const short8*)&pu.otile[64 + t][it * 8];
    *(short8*)(Vp + ((size_t)((pix0 >> 3) + it) * CC + t) * 8) = vv;
  }
}

// ---------------------------------------------------------------------------
// Kernel 2: implicit-GEMM MFMA conv, 512-thread blocks for occupancy.
// Block = 128 o x 256 pix (4 image rows). 8 waves: wm = w>>2 (o-half),
// wp = w&3 (row). Wave = 64 o x 64 pix. W (A-frags) direct from global/L2,
// pixels (B-frags) from LDS halo tile xs[6 rows][66][72]. R output bf16.
// grid (2 ob, 8 img, 16 pb) = 256 blocks, 2 blocks/CU = 16 waves/CU.
// ---------------------------------------------------------------------------
__global__ __launch_bounds__(512, 4) void conv_kernel(
    const unsigned short* __restrict__ Xp, const unsigned short* __restrict__ Wp,
    const float* __restrict__ bd1, const float* __restrict__ bd3,
    unsigned short* __restrict__ R1, unsigned short* __restrict__ R2) {
  const int t = threadIdx.x;
  const int w = t >> 6, lane = t & 63;
  const int l15 = lane & 15, g = lane >> 4;
  const int ob = blockIdx.x, img = blockIdx.y, pb = blockIdx.z;
  const int o0 = ob * 128, y0 = pb * 4;
  const int wm = w >> 2, wp = w & 3;

  const unsigned short* Xi = Xp + (size_t)img * NN * CC;
  unsigned short* R = ((img >> 2) ? R2 : R1) + (size_t)(img & 3) * CC * NN;

  __shared__ unsigned short xs[6][66][72];  // rows y0-1..y0+4, cols -1..64

  floatx4 ac[4][4];
#pragma unroll
  for (int m = 0; m < 4; ++m)
#pragma unroll
    for (int n = 0; n < 4; ++n) ac[m][n] = (floatx4){0.f, 0.f, 0.f, 0.f};

  for (int cb = 0; cb < 4; ++cb) {
    const int c0 = cb * 64;
    if (cb) __syncthreads();
#pragma unroll
    for (int it = 0; it < 7; ++it) {
      int id = it * 512 + t;
      if (id < 3168) {                 // 6*66*8 16B-chunks
        int r = id / 528, rem = id % 528;
        int col = rem >> 3, cc = rem & 7;
        int y = y0 - 1 + r, xx = col - 1;
        short8 v = {0, 0, 0, 0, 0, 0, 0, 0};
        if (y >= 0 && y < HH && xx >= 0 && xx < WW)
          v = *(const short8*)(Xi + (size_t)(y * WW + xx) * CC + c0 + cc * 8);
        *(short8*)&xs[r][col][cc * 8] = v;
      }
    }
    __syncthreads();
#pragma unroll
    for (int tap = 0; tap < 10; ++tap) {
      const int dy = (tap < 9) ? tap / 3 - 1 : 0;
      const int dx = (tap < 9) ? tap % 3 - 1 : 0;
      const int rrow = 1 + wp + dy;
      const unsigned short* wrow =
          Wp + ((size_t)tap * CC + o0 + wm * 64 + l15) * CC + c0 + g * 8;
#pragma unroll
      for (int ks = 0; ks < 2; ++ks) {
        short8 af[4], bf[4];
#pragma unroll
        for (int m = 0; m < 4; ++m)
          af[m] = *(const short8*)(wrow + (size_t)(m * 16) * CC + ks * 32);
#pragma unroll
        for (int n = 0; n < 4; ++n)
          bf[n] = *(const short8*)&xs[rrow][1 + n * 16 + l15 + dx][ks * 32 + g * 8];
#pragma unroll
        for (int m = 0; m < 4; ++m)
#pragma unroll
          for (int n = 0; n < 4; ++n)
            ac[m][n] = __builtin_amdgcn_mfma_f32_16x16x32_bf16(
                af[m], bf[n], ac[m][n], 0, 0, 0);
      }
    }
  }

  // epilogue: R[o][pix] = bf16(acc + bd1 + bd3)
#pragma unroll
  for (int m = 0; m < 4; ++m) {
    int ob2 = o0 + wm * 64 + m * 16 + g * 4;
    float bs[4];
#pragma unroll
    for (int r = 0; r < 4; ++r) bs[r] = bd1[ob2 + r] + bd3[ob2 + r];
#pragma unroll
    for (int n = 0; n < 4; ++n) {
      int pix = (y0 + wp) * WW + n * 16 + l15;
#pragma unroll
      for (int r = 0; r < 4; ++r)
        R[(size_t)(ob2 + r) * NN + pix] = (unsigned short)f2bf_fast(ac[m][n][r] + bs[r]);
    }
  }
}

// ---------------------------------------------------------------------------
// Kernel 3: one-pass MFMA flash attention, 512-thread blocks (8 waves).
// grid (2 att, 4 b, 64 i-blocks): id%8 = att+2b -> XCD-pinned V slice.
// Wave w: GEMM1 j-slice (w&3)*16 x i-half (w>>2)*32 (2 MFMAs);
//         GEMM2 c-slice w*32 x all 64 i (16 MFMAs). 1 barrier/tile, P dbuf,
// K dbuf registers, V single-buffer. Epilogue: out = x + gamma*(acc/l + R).
// ---------------------------------------------------------------------------
__global__ __launch_bounds__(512, 4) void attn_kernel(
    const unsigned short* __restrict__ Qp1, const unsigned short* __restrict__ Kp1,
    const unsigned short* __restrict__ Qp2, const unsigned short* __restrict__ Kp2,
    const unsigned short* __restrict__ Vp1, const unsigned short* __restrict__ Vp2,
    const unsigned short* __restrict__ R1, const unsigned short* __restrict__ R2,
    const float* __restrict__ x1, const float* __restrict__ x2,
    const float* __restrict__ g1, const float* __restrict__ g2,
    float* __restrict__ out) {
  const int t = threadIdx.x;
  const int w = t >> 6, lane = t & 63;
  const int l15 = lane & 15, g = lane >> 4;
  const int att = blockIdx.x, b = blockIdx.y;
  const int i0 = blockIdx.z * 64;
  const int jof = (w & 3) * 16;        // GEMM1 j-slice within tile
  const int ih32 = (w >> 2) * 32;      // GEMM1 i-half
  const int c0w = w * 32;              // GEMM2 c-slice

  const unsigned short *Qp, *Kp, *Vp, *Rb; const float *x; float gamma; float* o;
  if (att == 0) { Qp = Qp1; Kp = Kp2; Vp = Vp2; Rb = R1; x = x1; gamma = g1[0]; o = out; }
  else          { Qp = Qp2; Kp = Kp1; Vp = Vp1; Rb = R2; x = x2; gamma = g2[0];
                  o = out + (size_t)BB * CC * NN; }
  Qp += (size_t)b * NN * CKD; Kp += (size_t)b * NN * CKD; Vp += (size_t)b * NN * CC;
  Rb += (size_t)b * CC * NN; x += (size_t)b * CC * NN; o += (size_t)b * CC * NN;

  __shared__ unsigned short p_s[2][64][72];
  __shared__ float l_part[4][64];

  // Q B-frags for this wave's i-half (Q pre-scaled by log2e)
  short8 bq0 = *(const short8*)(Qp + (size_t)(i0 + ih32 + l15) * CKD + g * 8);
  short8 bq1 = *(const short8*)(Qp + (size_t)(i0 + ih32 + 16 + l15) * CKD + g * 8);

  floatx4 acc[4][2];
#pragma unroll
  for (int m = 0; m < 4; ++m)
#pragma unroll
    for (int cs = 0; cs < 2; ++cs) acc[m][cs] = (floatx4){0.f, 0.f, 0.f, 0.f};
  float l0 = 0.f, l1 = 0.f;
  const floatx4 zinit = {-EXPSHIFT, -EXPSHIFT, -EXPSHIFT, -EXPSHIFT};

  short8 kr0, kr1, vr[4];
  auto LOADK = [&](int tt, short8& d) {
    d = *(const short8*)(Kp + ((size_t)tt * 64 + jof + l15) * CKD + g * 8);
  };
  auto LOADV = [&](int tt) {
#pragma unroll
    for (int ks = 0; ks < 2; ++ks)
#pragma unroll
      for (int cs = 0; cs < 2; ++cs)
        vr[ks * 2 + cs] = *(const short8*)(Vp +
            (((size_t)tt * 8 + ks * 4 + g) * CC + (c0w + cs * 16 + l15)) * 8);
  };
  auto GEMM1 = [&](const short8& kf, unsigned short (*ps)[72]) {
    floatx4 s0 = __builtin_amdgcn_mfma_f32_16x16x32_bf16(kf, bq0, zinit, 0, 0, 0);
    floatx4 s1 = __builtin_amdgcn_mfma_f32_16x16x32_bf16(kf, bq1, zinit, 0, 0, 0);
    float p00 = fast_exp2(s0[0]), p01 = fast_exp2(s0[1]);
    float p02 = fast_exp2(s0[2]), p03 = fast_exp2(s0[3]);
    float p10 = fast_exp2(s1[0]), p11 = fast_exp2(s1[1]);
    float p12 = fast_exp2(s1[2]), p13 = fast_exp2(s1[3]);
    l0 += (p00 + p01) + (p02 + p03);
    l1 += (p10 + p11) + (p12 + p13);
    uint2 pk0, pk1;
    pk0.x = __builtin_amdgcn_perm(__float_as_uint(p01) + 0x8000u,
                                  __float_as_uint(p00) + 0x8000u, 0x07060302u);
    pk0.y = __builtin_amdgcn_perm(__float_as_uint(p03) + 0x8000u,
                                  __float_as_uint(p02) + 0x8000u, 0x07060302u);
    pk1.x = __builtin_amdgcn_perm(__float_as_uint(p11) + 0x8000u,
                                  __float_as_uint(p10) + 0x8000u, 0x07060302u);
    pk1.y = __builtin_amdgcn_perm(__float_as_uint(p13) + 0x8000u,
                                  __float_as_uint(p12) + 0x8000u, 0x07060302u);
    *(uint2*)&ps[ih32 + l15][jof + g * 4] = pk0;
    *(uint2*)&ps[ih32 + 16 + l15][jof + g * 4] = pk1;
  };
  auto GEMM2 = [&](unsigned short (*ps)[72]) {
#pragma unroll
    for (int ks = 0; ks < 2; ++ks) {
      short8 ap[4];
#pragma unroll
      for (int m = 0; m < 4; ++m)
        ap[m] = *(const short8*)&ps[m * 16 + l15][ks * 32 + g * 8];
#pragma unroll
      for (int cs = 0; cs < 2; ++cs)
#pragma unroll
        for (int m = 0; m < 4; ++m)
          acc[m][cs] = __builtin_amdgcn_mfma_f32_16x16x32_bf16(
              ap[m], vr[ks * 2 + cs], acc[m][cs], 0, 0, 0);
    }
  };

  // prologue
  LOADK(0, kr0); LOADK(1, kr1);
  GEMM1(kr0, p_s[0]);
  __syncthreads();

  for (int jt = 0; jt < 64; jt += 2) {
    // region A: GEMM2(jt) from p_s[0], GEMM1(jt+1) -> p_s[1]
    LOADV(jt);
    if (jt + 2 < 64) LOADK(jt + 2, kr0);
    GEMM1(kr1, p_s[1]);
    GEMM2(p_s[0]);
    __syncthreads();
    // region B: GEMM2(jt+1) from p_s[1], GEMM1(jt+2) -> p_s[0]
    LOADV(jt + 1);
    if (jt + 3 < 64) LOADK(jt + 3, kr1);
    if (jt + 2 < 64) GEMM1(kr0, p_s[0]);
    GEMM2(p_s[1]);
    __syncthreads();
  }

  // l: reduce over g, publish per (j-slice, i)
  l0 += __shfl_xor(l0, 16); l0 += __shfl_xor(l0, 32);
  l1 += __shfl_xor(l1, 16); l1 += __shfl_xor(l1, 32);
  if (g == 0) {
    l_part[w & 3][ih32 + l15] = l0;
    l_part[w & 3][ih32 + 16 + l15] = l1;
  }
  __syncthreads();

  // epilogue: out[c][i] = x + gamma*(acc/l + R)
#pragma unroll
  for (int m = 0; m < 4; ++m) {
    float linv[4];
#pragma unroll
    for (int r = 0; r < 4; ++r) {
      int il = m * 16 + g * 4 + r;
      linv[r] = 1.f / (l_part[0][il] + l_part[1][il] + l_part[2][il] + l_part[3][il]);
    }
#pragma unroll
    for (int cs = 0; cs < 2; ++cs) {
      int c = c0w + cs * 16 + l15;
      size_t base = (size_t)c * NN + i0 + m * 16 + g * 4;
      float4 xr = *(const float4*)(x + base);
      uint2 rr = *(const uint2*)(Rb + base);
      float4 ov;
      ov.x = xr.x + gamma * (acc[m][cs][0] * linv[0] + bf_lo(rr.x));
      ov.y = xr.y + gamma * (acc[m][cs][1] * linv[1] + bf_hi(rr.x));
      ov.z = xr.z + gamma * (acc[m][cs][2] * linv[2] + bf_lo(rr.y));
      ov.w = xr.w + gamma * (acc[m][cs][3] * linv[3] + bf_hi(rr.y));
      *(float4*)(o + base) = ov;
    }
  }
}

// ---------------------------------------------------------------------------
extern "C" void kernel_launch(void* const* d_in, const int* in_sizes, int n_in,
                              void* d_out, int out_size, void* d_ws, size_t ws_size,
                              hipStream_t stream) {
  const float* x1  = (const float*)d_in[0];
  const float* x2  = (const float*)d_in[1];
  const float* wq1 = (const float*)d_in[2];
  const float* bq1 = (const float*)d_in[3];
  const float* wk1 = (const float*)d_in[4];
  const float* bk1 = (const float*)d_in[5];
  const float* wv1 = (const float*)d_in[6];
  const float* bv1 = (const float*)d_in[7];
  const float* wq2 = (const float*)d_in[8];
  const float* bq2 = (const float*)d_in[9];
  const float* wk2 = (const float*)d_in[10];
  const float* bk2 = (const float*)d_in[11];
  const float* wv2 = (const float*)d_in[12];
  const float* bv2 = (const float*)d_in[13];
  const float* wd1 = (const float*)d_in[14];
  const float* bd1 = (const float*)d_in[15];
  const float* wd3 = (const float*)d_in[16];
  const float* bd3 = (const float*)d_in[17];
  const float* g1  = (const float*)d_in[18];
  const float* g2  = (const float*)d_in[19];
  float* out = (float*)d_out;

  // workspace layout (bytes)
  const size_t QB = (size_t)BB * NN * CKD * 2;     // 1 MB each
  const size_t VB = (size_t)BB * NN * CC * 2;      // 8 MB each
  const size_t RB = (size_t)BB * NN * CC * 2;      // 8 MB each (bf16)
  const size_t XB = (size_t)2 * BB * NN * CC * 2;  // 16 MB
  const size_t WPB = (size_t)10 * CC * CC * 2;     // 1.31 MB
  const size_t WQB = (size_t)2 * 320 * CC * 2;     // 320 KB
  char* base = (char*)d_ws;
  unsigned short* R1 = (unsigned short*)(base);
  unsigned short* R2 = (unsigned short*)(base + RB);
  unsigned short* Qp1 = (unsigned short*)(base + 2 * RB);
  unsigned short* Kp1 = (unsigned short*)(base + 2 * RB + QB);
  unsigned short* Qp2 = (unsigned short*)(base + 2 * RB + 2 * QB);
  unsigned short* Kp2 = (unsigned short*)(base + 2 * RB + 3 * QB);
  unsigned short* Vp1 = (unsigned short*)(base + 2 * RB + 4 * QB);
  unsigned short* Vp2 = (unsigned short*)(base + 2 * RB + 4 * QB + VB);
  unsigned short* Xp  = (unsigned short*)(base + 2 * RB + 4 * QB + 2 * VB);
  unsigned short* Wp  = (unsigned short*)(base + 2 * RB + 4 * QB + 2 * VB + XB);
  unsigned short* Wqkv = (unsigned short*)(base + 2 * RB + 4 * QB + 2 * VB + XB + WPB);
  float* Bias = (float*)(base + 2 * RB + 4 * QB + 2 * VB + XB + WPB + WQB);

  wpack_kernel<<<dim3(CC * CC / 256), 256, 0, stream>>>(
      wd1, wd3, wq1, wk1, wv1, wq2, wk2, wv2,
      bq1, bk1, bv1, bq2, bk2, bv2, Wp, Wqkv, Bias);

  proj_kernel<<<dim3(2 * BB, NN / 64), 256, 0, stream>>>(
      x1, x2, Wqkv, Bias, Xp, Qp1, Kp1, Vp1, Qp2, Kp2, Vp2);

  conv_kernel<<<dim3(2, 2 * BB, HH / 4), 512, 0, stream>>>(
      Xp, Wp, bd1, bd3, R1, R2);

  attn_kernel<<<dim3(2, BB, NN / 64), 512, 0, stream>>>(
      Qp1, Kp1, Qp2, Kp2, Vp1, Vp2, R1, R2, x1, x2, g1, g2, out);
}